// Round 9
// baseline (200.290 us; speedup 1.0000x reference)
//
#include <hip/hip_runtime.h>
#include <hip/hip_bf16.h>
#include <math.h>
#include <stdint.h>

// Problem constants
constexpr int BATCH  = 2;
constexpr int SEQ    = 2048;
constexpr int DMODEL = 768;
constexpr int NH     = 12;
constexpr int HD     = 64;           // head dim
constexpr int NTOK   = BATCH * SEQ;  // 4096
constexpr float LOG2E = 1.4426950408889634f;

typedef __attribute__((ext_vector_type(8))) short     short8;  // 8 bf16
typedef __attribute__((ext_vector_type(8))) _Float16  half8;   // 8 fp16
typedef __attribute__((ext_vector_type(4))) float     floatx4;

#define DEVINL __device__ __forceinline__

DEVINL floatx4 mfma16(short8 a, short8 b, floatx4 c) {
    return __builtin_amdgcn_mfma_f32_16x16x32_bf16(a, b, c, 0, 0, 0);
}
DEVINL floatx4 mfma16h(half8 a, half8 b, floatx4 c) {
    return __builtin_amdgcn_mfma_f32_16x16x32_f16(a, b, c, 0, 0, 0);
}
DEVINL __hip_bfloat16 f2b(float x) { return __float2bfloat16(x); }

// async global->LDS, 16B per lane; l must be wave-uniform (dest = l + lane*16)
DEVINL void load16_lds(const void* g, void* l) {
    __builtin_amdgcn_global_load_lds(
        reinterpret_cast<const __attribute__((address_space(1))) unsigned int*>(
            reinterpret_cast<uintptr_t>(g)),
        reinterpret_cast<__attribute__((address_space(3))) unsigned int*>(
            reinterpret_cast<uintptr_t>(l)),
        16, 0, 0);
}

// ---------------------------------------------------------------------------
// Prep (merged): z<4: W[k][n] f32 -> Wt[n][k] fp16 (z==0 pre-scaled log2e);
// z>=4: input f32 -> fp16 flat copy. grid (24,24,7), block 256.
// ---------------------------------------------------------------------------
__global__ void prep_k(const float* __restrict__ W0, const float* __restrict__ W1,
                       const float* __restrict__ W2, const float* __restrict__ W3,
                       _Float16* H0, _Float16* H1, _Float16* H2, _Float16* H3,
                       const float* __restrict__ q, const float* __restrict__ k,
                       const float* __restrict__ v,
                       _Float16* qf, _Float16* kf, _Float16* vf) {
    int z = blockIdx.z;
    int tid = threadIdx.x;
    if (z < 4) {
        const float* W = (z == 0) ? W0 : (z == 1) ? W1 : (z == 2) ? W2 : W3;
        _Float16* H = (z == 0) ? H0 : (z == 1) ? H1 : (z == 2) ? H2 : H3;
        float sc = (z == 0) ? LOG2E : 1.0f;
        __shared__ float t[32][33];
        int k0 = blockIdx.x * 32, n0 = blockIdx.y * 32;
        int tx = tid & 31, ty = tid >> 5;
        for (int i = ty; i < 32; i += 8)
            t[i][tx] = W[(size_t)(k0 + i) * DMODEL + n0 + tx];
        __syncthreads();
        for (int i = ty; i < 32; i += 8)
            H[(size_t)(n0 + i) * DMODEL + k0 + tx] = (_Float16)(t[tx][i] * sc);
    } else {
        const float* src = (z == 4) ? q : (z == 5) ? k : v;
        _Float16* dst = (z == 4) ? qf : (z == 5) ? kf : vf;
        constexpr int NCH = NTOK * DMODEL / 8;       // 393216 chunks of 8
        int flat = (blockIdx.y * 24 + blockIdx.x) * 256 + tid;
        for (int c = flat; c < NCH; c += 24 * 24 * 256) {
            size_t base = (size_t)c * 8;
            float4 a = *(const float4*)(src + base);
            float4 b = *(const float4*)(src + base + 4);
            half8 o;
            o[0] = (_Float16)a.x; o[1] = (_Float16)a.y;
            o[2] = (_Float16)a.z; o[3] = (_Float16)a.w;
            o[4] = (_Float16)b.x; o[5] = (_Float16)b.y;
            o[6] = (_Float16)b.z; o[7] = (_Float16)b.w;
            *(half8*)(dst + base) = o;
        }
    }
}

// ---------------------------------------------------------------------------
// Stage one 128x64 A-tile + 64x64 B-tile (2B elems) into a 24KB LDS buffer,
// XOR-source-swizzled so frag reads are conflict-free. 6 async instrs/wave.
// ---------------------------------------------------------------------------
DEVINL void stage_ab(const uint16_t* A, const uint16_t* B,
                     char* buf, int m0, int n0, int k0, int tid, int wv) {
#pragma unroll
    for (int i = 0; i < 4; ++i) {
        int e = i * 256 + tid;
        int row = e >> 3, c8 = (e & 7) ^ (row & 7);
        load16_lds(A + (size_t)(m0 + row) * DMODEL + k0 + c8 * 8,
                   buf + i * 4096 + wv * 1024);
    }
#pragma unroll
    for (int i = 0; i < 2; ++i) {
        int e = i * 256 + tid;
        int row = e >> 3, c8 = (e & 7) ^ (row & 7);
        load16_lds(B + (size_t)(n0 + row) * DMODEL + k0 + c8 * 8,
                   buf + 16384 + i * 4096 + wv * 1024);
    }
}

// ---------------------------------------------------------------------------
// Fused QKV projection (fp16 single-term), double-buffered prefetch.
// grid (32, 12, 3), block 256 (2x2 waves), tile 128x64, BK=64, 12 steps.
// z=0: Q (W pre-scaled log2e) -> fp16 [b][h][s][d]   (swizzled-LDS epilogue)
// z=1: K -> fp16 [b][h][s][d]                        (swizzled-LDS epilogue)
// z=2: V -> bf16 V^T [b][h][d][s]                    (LDS-transpose epilogue)
// ---------------------------------------------------------------------------
__global__ __launch_bounds__(256) void gemm_qkv(
    const uint16_t* __restrict__ qf, const uint16_t* __restrict__ kf,
    const uint16_t* __restrict__ vf,
    const uint16_t* __restrict__ Wq, const uint16_t* __restrict__ Wk,
    const uint16_t* __restrict__ Wv,
    const float* __restrict__ bq, const float* __restrict__ bk,
    const float* __restrict__ bv,
    _Float16* Qf, _Float16* Kf, __hip_bfloat16* Vt) {
    __shared__ __align__(16) char smem[49152];  // 2 x 24KB

    int z = blockIdx.z;
    const uint16_t* A = (z == 0) ? qf : (z == 1) ? kf : vf;
    const uint16_t* B = (z == 0) ? Wq : (z == 1) ? Wk : Wv;
    const float* bias = (z == 0) ? bq : (z == 1) ? bk : bv;
    float bscale = (z == 0) ? LOG2E : 1.0f;

    int tid = threadIdx.x;
    int wv = tid >> 6, lane = tid & 63, quad = lane >> 4, ln = lane & 15;
    int mw = wv & 1, nw = wv >> 1;
    int m0 = blockIdx.x * 128, n0 = blockIdx.y * 64;
    int sw = (ln & 7) * 16;

    floatx4 acc[4][2];
#pragma unroll
    for (int f = 0; f < 4; ++f)
#pragma unroll
        for (int g = 0; g < 2; ++g) acc[f][g] = floatx4{0.f, 0.f, 0.f, 0.f};

    stage_ab(A, B, smem, m0, n0, 0, tid, wv);

    for (int s = 0; s < 12; ++s) {
        __syncthreads();
        if (s + 1 < 12)
            stage_ab(A, B, smem + ((s + 1) & 1) * 24576, m0, n0, (s + 1) * 64, tid, wv);
        char* buf = smem + (s & 1) * 24576;
#pragma unroll
        for (int ks = 0; ks < 2; ++ks) {
            half8 ah[4], bh2[2];
#pragma unroll
            for (int f = 0; f < 4; ++f) {
                int row = mw * 64 + f * 16 + ln;
                ah[f] = *(const half8*)(buf + row * 128 + ((ks * 64 + quad * 16) ^ sw));
            }
#pragma unroll
            for (int g = 0; g < 2; ++g) {
                int row = nw * 32 + g * 16 + ln;
                bh2[g] = *(const half8*)(buf + 16384 + row * 128 + ((ks * 64 + quad * 16) ^ sw));
            }
#pragma unroll
            for (int f = 0; f < 4; ++f)
#pragma unroll
                for (int g = 0; g < 2; ++g)
                    acc[f][g] = mfma16h(ah[f], bh2[g], acc[f][g]);
        }
    }
    __syncthreads();  // done reading staging buffers

    int b = m0 >> 11, s0 = m0 & (SEQ - 1), h = n0 >> 6;
    if (z == 2) {
        __hip_bfloat16* T = (__hip_bfloat16*)smem;  // [64][136]
#pragma unroll
        for (int f = 0; f < 4; ++f)
#pragma unroll
            for (int g = 0; g < 2; ++g) {
                int nl = nw * 32 + g * 16 + ln;
                float bvv = bias[n0 + nl];
#pragma unroll
                for (int rr = 0; rr < 4; ++rr) {
                    int ml = mw * 64 + f * 16 + quad * 4 + rr;
                    T[nl * 136 + ml] = f2b(acc[f][g][rr] + bvv);
                }
            }
        __syncthreads();
        __hip_bfloat16* dst = Vt + (size_t)(b * NH + h) * HD * SEQ;
#pragma unroll
        for (int i = 0; i < 4; ++i) {
            int cid = i * 256 + tid;
            int d = cid >> 4, ch = cid & 15;
            short8 v = *(const short8*)(T + d * 136 + ch * 8);
            *(short8*)(dst + (size_t)d * SEQ + s0 + ch * 8) = v;
        }
    } else {
        _Float16* o0 = (z == 0) ? Qf : Kf;
        // [128][64] fp16, group (nl>>3) xor-swizzled by (ml&7): conflict-free
        uint16_t* T = (uint16_t*)smem;  // 16KB
#pragma unroll
        for (int f = 0; f < 4; ++f)
#pragma unroll
            for (int g = 0; g < 2; ++g) {
                int nl = nw * 32 + g * 16 + ln;
                float bvv = bias[n0 + nl] * bscale;
#pragma unroll
                for (int rr = 0; rr < 4; ++rr) {
                    int ml = mw * 64 + f * 16 + quad * 4 + rr;
                    int phys = (((nl >> 3) ^ (ml & 7)) << 3) | (nl & 7);
                    _Float16 hv = (_Float16)(acc[f][g][rr] + bvv);
                    T[ml * 64 + phys] = *(uint16_t*)&hv;
                }
            }
        __syncthreads();
        _Float16* dst = o0 + ((size_t)(b * NH + h) * SEQ + s0) * HD;
#pragma unroll
        for (int i = 0; i < 4; ++i) {
            int cid = i * 256 + tid;
            int row = cid >> 3, j = cid & 7;
            short8 v = *(const short8*)(T + row * 64 + ((j ^ (row & 7)) << 3));
            *(short8*)(dst + (size_t)row * HD + j * 8) = v;
        }
    }
}

// ---------------------------------------------------------------------------
// Flash attention, NO-MAX streaming softmax (exp2 domain; Q pre-scaled log2e).
// Q,K: fp16 [b*h][s][64]; V: bf16 [b*h][64][s] (transposed); P: bf16.
// block 256 = 4 waves; q-tile 128 (32 rows/wave); KV tile 64, double-buffered.
// grid (24, 24) -- round-6 formula decode (KNOWN GOOD; the 40-slot LPT table
// variant fails correctness (r7/r8, absmax~2.7) despite passing static proof;
// quarantined pending a device-side probe).
//  slot 0..15: qti=15-(slot>>1), half=slot&1: kv [half*(qti+1), +qti+1)
//  slot 16..23: qti=23-slot: kv [0, 2qti+2)
// Partials atomically added into f32 Oacc/Lacc (additive: no-max softmax).
// ---------------------------------------------------------------------------
__global__ __launch_bounds__(256) void flash_k(
    const _Float16* __restrict__ Qf, const _Float16* __restrict__ Kf,
    const __hip_bfloat16* __restrict__ Vt,
    float* __restrict__ Oacc, float* __restrict__ Lacc) {
    int slot = blockIdx.x, bh = blockIdx.y;
    int qti, kv0, kv1;
    if (slot < 16) {
        qti = 15 - (slot >> 1);
        int hf = slot & 1;
        kv0 = hf * (qti + 1);
        kv1 = kv0 + qti + 1;
    } else {
        qti = 23 - slot;
        kv0 = 0;
        kv1 = 2 * qti + 2;
    }

    int tid = threadIdx.x;
    int wv = tid >> 6, lane = tid & 63, quad = lane >> 4, ln = lane & 15;
    int sw = (ln & 7) * 16;

    const _Float16* Qb = Qf + (size_t)bh * SEQ * HD;
    const uint16_t* Kb = (const uint16_t*)Kf + (size_t)bh * SEQ * HD;
    const uint16_t* Vb = (const uint16_t*)Vt + (size_t)bh * HD * SEQ;

    int qr0 = qti * 128 + wv * 32;

    // 2 x (K 8K | V 8K) double buffer + per-wave P (16x72 bf16)
    __shared__ __align__(16) char smem[32768 + 4 * 16 * 72 * 2];
    __hip_bfloat16* sP = (__hip_bfloat16*)(smem + 32768) + wv * 16 * 72;

    auto stage = [&](int kv, int bsel) {
        char* buf = smem + bsel * 16384;
        int kb = kv * 64;
#pragma unroll
        for (int i = 0; i < 2; ++i) {
            int e = i * 256 + tid;
            int row = e >> 3, c8 = (e & 7) ^ (row & 7);
            int ldso = i * 4096 + wv * 1024;
            load16_lds(Kb + (size_t)(kb + row) * HD + c8 * 8, buf + ldso);
            load16_lds(Vb + (size_t)row * SEQ + kb + c8 * 8, buf + 8192 + ldso);
        }
    };

    stage(kv0, 0);

    half8 aQ[2][2];
#pragma unroll
    for (int rg = 0; rg < 2; ++rg)
#pragma unroll
        for (int ks = 0; ks < 2; ++ks)
            aQ[rg][ks] = *(const half8*)(Qb + (size_t)(qr0 + rg * 16 + ln) * HD +
                                         ks * 32 + quad * 8);

    short8 vone;
#pragma unroll
    for (int i = 0; i < 8; ++i) vone[i] = (short)0x3F80;  // bf16 1.0

    floatx4 accO[2][4], accL[2];
#pragma unroll
    for (int rg = 0; rg < 2; ++rg) {
        accL[rg] = floatx4{0.f, 0.f, 0.f, 0.f};
#pragma unroll
        for (int j = 0; j < 4; ++j) accO[rg][j] = floatx4{0.f, 0.f, 0.f, 0.f};
    }

    for (int kv = kv0; kv < kv1; ++kv) {
        int ib = (kv - kv0) & 1;
        __syncthreads();  // tile kv ready (prefetch issued last iter)
        if (kv + 1 < kv1) stage(kv + 1, ib ^ 1);
        const char* sK = smem + ib * 16384;
        const char* sV = sK + 8192;
        int kb = kv * 64;

        // ---- S = Q K^T (fp16 single-term), exp2-domain ----
        floatx4 accS[2][4];
#pragma unroll
        for (int rg = 0; rg < 2; ++rg)
#pragma unroll
            for (int cc = 0; cc < 4; ++cc) accS[rg][cc] = floatx4{0.f, 0.f, 0.f, 0.f};
#pragma unroll
        for (int cc = 0; cc < 4; ++cc)
#pragma unroll
            for (int ks = 0; ks < 2; ++ks) {
                int off = (cc * 16 + ln) * 128 + ((ks * 64 + quad * 16) ^ sw);
                half8 bK = *(const half8*)(sK + off);
                accS[0][cc] = mfma16h(aQ[0][ks], bK, accS[0][cc]);
                accS[1][cc] = mfma16h(aQ[1][ks], bK, accS[1][cc]);
            }

        // ---- softmax (no max, no reductions) + P->LDS per rg ----
        short8 aP[2][2];
#pragma unroll
        for (int rg = 0; rg < 2; ++rg) {
            bool domask = (kb + 63 > qr0 + rg * 16);
#pragma unroll
            for (int rr = 0; rr < 4; ++rr) {
                int qg = qr0 + rg * 16 + quad * 4 + rr;
#pragma unroll
                for (int cc = 0; cc < 4; ++cc) {
                    float s = accS[rg][cc][rr];
                    if (domask && (kb + cc * 16 + ln > qg)) s = -INFINITY;
                    sP[(quad * 4 + rr) * 72 + cc * 16 + ln] =
                        f2b(__builtin_amdgcn_exp2f(s));
                }
            }
#pragma unroll
            for (int ks = 0; ks < 2; ++ks)
                aP[rg][ks] = *(const short8*)(sP + ln * 72 + ks * 32 + quad * 8);
            // l via ones-MFMA (off the VALU pipe)
            accL[rg] = mfma16(aP[rg][0], vone, accL[rg]);
            accL[rg] = mfma16(aP[rg][1], vone, accL[rg]);
        }

        // ---- O += P V (V-frags shared across both row groups) ----
#pragma unroll
        for (int cc = 0; cc < 4; ++cc)
#pragma unroll
            for (int ks = 0; ks < 2; ++ks) {
                int off = (cc * 16 + ln) * 128 + ((ks * 64 + quad * 16) ^ sw);
                short8 bV = *(const short8*)(sV + off);
                accO[0][cc] = mfma16(aP[0][ks], bV, accO[0][cc]);
                accO[1][cc] = mfma16(aP[1][ks], bV, accO[1][cc]);
            }
    }

    // ---- epilogue: atomic-add partials ----
    float* Ob = Oacc + (size_t)bh * SEQ * HD;
#pragma unroll
    for (int rg = 0; rg < 2; ++rg)
#pragma unroll
        for (int cc = 0; cc < 4; ++cc)
#pragma unroll
            for (int rr = 0; rr < 4; ++rr) {
                int s = qr0 + rg * 16 + quad * 4 + rr;
                unsafeAtomicAdd(&Ob[(size_t)s * HD + cc * 16 + ln], accO[rg][cc][rr]);
            }
    if (ln == 0) {
#pragma unroll
        for (int rg = 0; rg < 2; ++rg)
#pragma unroll
            for (int rr = 0; rr < 4; ++rr)
                unsafeAtomicAdd(&Lacc[bh * SEQ + qr0 + rg * 16 + quad * 4 + rr],
                                accL[rg][rr]);
    }
}

// ---------------------------------------------------------------------------
// Combine: attn[b][s][h*64+d] = Oacc[bh][s][d] / Lacc[bh][s]  (f32 -> fp16)
// grid 1536, block 256; 8 d-elements per thread.
// ---------------------------------------------------------------------------
__global__ void combine_k(const float* __restrict__ Oacc, const float* __restrict__ Lacc,
                          _Float16* __restrict__ attn) {
    int idx = blockIdx.x * 256 + threadIdx.x;
    int d8 = idx & 7;
    int rest = idx >> 3;
    int s = rest & (SEQ - 1);
    int bh = rest >> 11;
    int b = bh / NH, h = bh % NH;
    float inv = 1.0f / Lacc[bh * SEQ + s];
    const float* src = Oacc + ((size_t)bh * SEQ + s) * HD + d8 * 8;
    float4 a = *(const float4*)src;
    float4 c = *(const float4*)(src + 4);
    half8 o;
    o[0] = (_Float16)(a.x * inv); o[1] = (_Float16)(a.y * inv);
    o[2] = (_Float16)(a.z * inv); o[3] = (_Float16)(a.w * inv);
    o[4] = (_Float16)(c.x * inv); o[5] = (_Float16)(c.y * inv);
    o[6] = (_Float16)(c.z * inv); o[7] = (_Float16)(c.w * inv);
    *(half8*)(attn + ((size_t)(b * SEQ + s)) * DMODEL + h * HD + d8 * 8) = o;
}

// ---------------------------------------------------------------------------
// Output projection: out f32 [4096][768] = attn(fp16) @ W_o + b_o
// tile 128x64, BK=64, grid (32,12), block 256, double-buffered prefetch,
// f32 epilogue through xor-swizzled LDS -> float4 coalesced stores.
// ---------------------------------------------------------------------------
__global__ __launch_bounds__(256) void gemm_o(
    const uint16_t* __restrict__ A, const uint16_t* __restrict__ B,
    const float* __restrict__ bias, float* __restrict__ out) {
    __shared__ __align__(16) char smem[49152];

    int tid = threadIdx.x;
    int wv = tid >> 6, lane = tid & 63, quad = lane >> 4, ln = lane & 15;
    int mw = wv & 1, nw = wv >> 1;
    int m0 = blockIdx.x * 128, n0 = blockIdx.y * 64;
    int sw = (ln & 7) * 16;

    floatx4 acc[4][2];
#pragma unroll
    for (int f = 0; f < 4; ++f)
#pragma unroll
        for (int g = 0; g < 2; ++g) acc[f][g] = floatx4{0.f, 0.f, 0.f, 0.f};

    stage_ab(A, B, smem, m0, n0, 0, tid, wv);

    for (int s = 0; s < 12; ++s) {
        __syncthreads();
        if (s + 1 < 12)
            stage_ab(A, B, smem + ((s + 1) & 1) * 24576, m0, n0, (s + 1) * 64, tid, wv);
        char* buf = smem + (s & 1) * 24576;
#pragma unroll
        for (int ks = 0; ks < 2; ++ks) {
            half8 ah[4], bh2[2];
#pragma unroll
            for (int f = 0; f < 4; ++f) {
                int row = mw * 64 + f * 16 + ln;
                ah[f] = *(const half8*)(buf + row * 128 + ((ks * 64 + quad * 16) ^ sw));
            }
#pragma unroll
            for (int g = 0; g < 2; ++g) {
                int row = nw * 32 + g * 16 + ln;
                bh2[g] = *(const half8*)(buf + 16384 + row * 128 + ((ks * 64 + quad * 16) ^ sw));
            }
#pragma unroll
            for (int f = 0; f < 4; ++f)
#pragma unroll
                for (int g = 0; g < 2; ++g)
                    acc[f][g] = mfma16h(ah[f], bh2[g], acc[f][g]);
        }
    }
    __syncthreads();
    // [128][64] f32, 16B-group (nl>>2) xor-swizzled by (ml&15)
    float* T = (float*)smem;  // 32KB
#pragma unroll
    for (int f = 0; f < 4; ++f)
#pragma unroll
        for (int g = 0; g < 2; ++g) {
            int nl = nw * 32 + g * 16 + ln;
            float bvv = bias[n0 + nl];
#pragma unroll
            for (int rr = 0; rr < 4; ++rr) {
                int ml = mw * 64 + f * 16 + quad * 4 + rr;
                int phys = (((nl >> 2) ^ (ml & 15)) << 2) | (nl & 3);
                T[ml * 64 + phys] = acc[f][g][rr] + bvv;
            }
        }
    __syncthreads();
#pragma unroll
    for (int i = 0; i < 8; ++i) {
        int cid = i * 256 + tid;
        int row = cid >> 4, j = cid & 15;
        float4 v = *(const float4*)(T + row * 64 + ((j ^ (row & 15)) << 2));
        *(float4*)(out + (size_t)(m0 + row) * DMODEL + n0 + j * 4) = v;
    }
}

// ---------------------------------------------------------------------------
extern "C" void kernel_launch(void* const* d_in, const int* in_sizes, int n_in,
                              void* d_out, int out_size, void* d_ws, size_t ws_size,
                              hipStream_t stream) {
    const float* query = (const float*)d_in[0];
    const float* key_  = (const float*)d_in[1];
    const float* value = (const float*)d_in[2];
    // d_in[3] = mask (causal; known analytically, unused)
    const float* W_q = (const float*)d_in[4];
    const float* b_q = (const float*)d_in[5];
    const float* W_k = (const float*)d_in[6];
    const float* b_k = (const float*)d_in[7];
    const float* W_v = (const float*)d_in[8];
    const float* b_v = (const float*)d_in[9];
    const float* W_o = (const float*)d_in[10];
    const float* b_o = (const float*)d_in[11];

    constexpr size_t WSZ = (size_t)DMODEL * DMODEL;       // 589824
    constexpr size_t QSZ = (size_t)BATCH * NH * SEQ * HD; // 3145728
    constexpr size_t OSZ = QSZ;                           // f32 O-accum elems
    constexpr size_t LSZ = (size_t)BATCH * NH * SEQ;      // 49152

    char* w = (char*)d_ws;
    _Float16* Wq = (_Float16*)w; w += WSZ * 2;
    _Float16* Wk = (_Float16*)w; w += WSZ * 2;
    _Float16* Wv = (_Float16*)w; w += WSZ * 2;
    _Float16* Wo = (_Float16*)w; w += WSZ * 2;
    _Float16* qf = (_Float16*)w; w += QSZ * 2;
    _Float16* kf = (_Float16*)w; w += QSZ * 2;
    _Float16* vf = (_Float16*)w; w += QSZ * 2;
    _Float16* Qf_ = (_Float16*)w; w += QSZ * 2;
    _Float16* Kf_ = (_Float16*)w; w += QSZ * 2;
    __hip_bfloat16* Vt_ = (__hip_bfloat16*)w; w += QSZ * 2;
    _Float16* attn_ = (_Float16*)w; w += QSZ * 2;
    // f32 partial buffers overlay dead qf/kf/vf region (zeroed after gemm_qkv)
    float* Oacc = (float*)qf;            // 12.58 MB (spans qf+kf)
    float* Lacc = Oacc + OSZ;            // 0.19 MB (spills into vf -- dead too)

    prep_k<<<dim3(24, 24, 7), 256, 0, stream>>>(
        W_q, W_k, W_v, W_o, Wq, Wk, Wv, Wo, query, key_, value, qf, kf, vf);

    gemm_qkv<<<dim3(NTOK / 128, DMODEL / 64, 3), 256, 0, stream>>>(
        (const uint16_t*)qf, (const uint16_t*)kf, (const uint16_t*)vf,
        (const uint16_t*)Wq, (const uint16_t*)Wk, (const uint16_t*)Wv,
        b_q, b_k, b_v, Qf_, Kf_, Vt_);

    (void)hipMemsetAsync(Oacc, 0, (OSZ + LSZ) * sizeof(float), stream);

    flash_k<<<dim3(24, BATCH * NH), 256, 0, stream>>>(Qf_, Kf_, Vt_, Oacc, Lacc);

    combine_k<<<dim3(BATCH * NH * SEQ * 8 / 256), 256, 0, stream>>>(Oacc, Lacc, attn_);

    gemm_o<<<dim3(NTOK / 128, DMODEL / 64), 256, 0, stream>>>(
        (const uint16_t*)attn_, (const uint16_t*)Wo, b_o, (float*)d_out);
}